// Round 9
// baseline (139.454 us; speedup 1.0000x reference)
//
#include <hip/hip_runtime.h>
#include <hip/hip_bf16.h>

// b=2, t=4096, emb=512, heads=8, head_dim=64.
// out = softmax((xWq^T)(xWk^T)^T / sqrt(512)) (xWv^T) Wu^T + bu
// Round 8: cross-tile software pipeline in attn. PV(tile i-1) executes during
// softmax(tile i): pa/vb of the previous tile stay in registers (explicit A/B
// sets, 2x-unrolled loop; no runtime indexing -> no scratch). PV is register-
// only, so the per-tile barrier structure of passing round 7 is unchanged.
// Pure instruction reordering — math bit-identical to round 7.

#define T 4096
#define HEADS 8
#define HD 64
#define EMB 512
#define BATCH 2
#define BH (BATCH * HEADS)
#define NT (T / 64)

typedef __attribute__((ext_vector_type(8))) short short8;
typedef __attribute__((ext_vector_type(4))) float floatx4;

// f32 -> bf16 round-to-nearest-even
__device__ inline short f2bf(float f) {
  union { float f; unsigned u; } v; v.f = f;
  unsigned r = v.u + 0x7FFF + ((v.u >> 16) & 1);
  return (short)(r >> 16);
}

__device__ inline short8 pack8(float4 a, float4 b) {
  short8 o;
  o[0] = f2bf(a.x); o[1] = f2bf(a.y); o[2] = f2bf(a.z); o[3] = f2bf(a.w);
  o[4] = f2bf(b.x); o[5] = f2bf(b.y); o[6] = f2bf(b.z); o[7] = f2bf(b.w);
  return o;
}

// 8 floats -> short8 bf16 via compiler-generated v_cvt_pk_bf16_f32
__device__ inline short8 packbf(const float* p) {
  union { __hip_bfloat162 h[4]; short8 s; } u;
  float2 t;
  t.x = p[0]; t.y = p[1]; u.h[0] = __float22bfloat162_rn(t);
  t.x = p[2]; t.y = p[3]; u.h[1] = __float22bfloat162_rn(t);
  t.x = p[4]; t.y = p[5]; u.h[2] = __float22bfloat162_rn(t);
  t.x = p[6]; t.y = p[7]; u.h[3] = __float22bfloat162_rn(t);
  return u.s;
}

// swizzled byte offset in a [rows][64] bf16 tile (row stride 128B)
__device__ inline int swz(int row, int byte) {
  return (row * 128 + byte) ^ ((row & 7) << 4);
}

// ---------------------------------------------------------------------------
// Kernel A (round-7 verbatim): q,k -> [bh][t][d]; v -> vt[bh][d][t''] with
// t'' = (t&~31)|((t>>2)&3)<<3|((t>>4)&1)<<2|(t&3) (PV slot order).
// ---------------------------------------------------------------------------
__global__ __launch_bounds__(256) void qkv_kernel(
    const float* __restrict__ x, const float* __restrict__ Wq,
    const float* __restrict__ Wk, const float* __restrict__ Wv,
    short* __restrict__ q_ws, short* __restrict__ k_ws, short* __restrict__ vt_ws) {
  __shared__ __align__(16) short xs[256 * 64];
  const int tid = threadIdx.x;
  const int lane = tid & 63;
  const int w = tid >> 6;
  const int g = lane >> 4, lr = lane & 15;
  const long rowbase = (long)blockIdx.x * 256;

  {
    const float4* xv = (const float4*)(x + (rowbase + tid) * 64);
    for (int c = 0; c < 8; ++c) {
      float4 a = xv[2 * c], b = xv[2 * c + 1];
      *(short8*)((char*)xs + swz(tid, c * 16)) = pack8(a, b);
    }
  }
  __syncthreads();

  const float* Ws[3] = {Wq, Wk, Wv};
  for (int m = 0; m < 3; ++m) {
    const float* W = Ws[m];
    for (int nt = 0; nt < 4; ++nt) {
      const int coln = nt * 16 + lr;
      const float4* wr0 = (const float4*)(W + coln * 64 + 8 * g);
      const float4* wr1 = (const float4*)(W + coln * 64 + 32 + 8 * g);
      short8 b0 = pack8(wr0[0], wr0[1]);
      short8 b1 = pack8(wr1[0], wr1[1]);
      for (int mr = 0; mr < 4; ++mr) {
        const int arow = w * 64 + mr * 16 + lr;
        short8 a0 = *(short8*)((char*)xs + swz(arow, g * 16));
        short8 a1 = *(short8*)((char*)xs + swz(arow, 64 + g * 16));
        floatx4 acc = 0;
        acc = __builtin_amdgcn_mfma_f32_16x16x32_bf16(a0, b0, acc, 0, 0, 0);
        acc = __builtin_amdgcn_mfma_f32_16x16x32_bf16(a1, b1, acc, 0, 0, 0);
        for (int jj = 0; jj < 4; ++jj) {
          long R = rowbase + w * 64 + mr * 16 + 4 * g + jj;
          int bb = (int)(R >> 15);
          int h = (int)(R & 7);
          int t = (int)((R >> 3) & 4095);
          if (m == 0)
            q_ws[(((long)(bb * HEADS + h) * T + t) * 64) + coln] = f2bf(acc[jj]);
          else if (m == 1)
            k_ws[(((long)(bb * HEADS + h) * T + t) * 64) + coln] = f2bf(acc[jj]);
          else {
            int tp = (t & ~31) | (((t >> 2) & 3) << 3) | (((t >> 4) & 1) << 2) | (t & 3);
            vt_ws[((long)(bb * HEADS + h) * 64 + coln) * T + tp] = f2bf(acc[jj]);
          }
        }
      }
    }
  }
}

// ---------------------------------------------------------------------------
// attn helpers (all register-level, force-inlined)
// ---------------------------------------------------------------------------
__device__ __forceinline__ void frag_loads(const char* KsB, const char* VsB,
    int lr, int g, short8 kb[4][2], short8 vb[4][2]) {
#pragma unroll
  for (int kt = 0; kt < 4; ++kt) {
    kb[kt][0] = *(const short8*)(KsB + swz(kt * 16 + lr, g * 16));
    kb[kt][1] = *(const short8*)(KsB + swz(kt * 16 + lr, 64 + g * 16));
  }
#pragma unroll
  for (int dt = 0; dt < 4; ++dt) {
    vb[dt][0] = *(const short8*)(VsB + swz(dt * 16 + lr, g * 16));
    vb[dt][1] = *(const short8*)(VsB + swz(dt * 16 + lr, 64 + g * 16));
  }
}

__device__ __forceinline__ void qkt_softmax(const short8 kb[4][2],
    const short8 aq[2][2], float c2, float ellp[2], short8 pa[2][2]) {
#pragma unroll
  for (int mt = 0; mt < 2; ++mt) {
    floatx4 s[4];
#pragma unroll
    for (int kt = 0; kt < 4; ++kt) {
      floatx4 z = 0;
      z = __builtin_amdgcn_mfma_f32_16x16x32_bf16(kb[kt][0], aq[mt][0], z, 0, 0, 0);
      z = __builtin_amdgcn_mfma_f32_16x16x32_bf16(kb[kt][1], aq[mt][1], z, 0, 0, 0);
      s[kt] = z;
    }
    float p[16];
#pragma unroll
    for (int kt = 0; kt < 4; ++kt)
#pragma unroll
      for (int r = 0; r < 4; ++r)
        p[kt * 4 + r] = __builtin_amdgcn_exp2f(fmaf(s[kt][r], c2, -3.0f));
#pragma unroll
    for (int e = 0; e < 16; ++e) ellp[mt] += p[e];
    pa[mt][0] = packbf(p);
    pa[mt][1] = packbf(p + 8);
  }
}

__device__ __forceinline__ void do_pv(const short8 pa[2][2],
    const short8 vb[4][2], floatx4 acc[2][4]) {
#pragma unroll
  for (int mt = 0; mt < 2; ++mt)
#pragma unroll
    for (int dt = 0; dt < 4; ++dt) {
      acc[mt][dt] = __builtin_amdgcn_mfma_f32_16x16x32_bf16(pa[mt][0], vb[dt][0], acc[mt][dt], 0, 0, 0);
      acc[mt][dt] = __builtin_amdgcn_mfma_f32_16x16x32_bf16(pa[mt][1], vb[dt][1], acc[mt][dt], 0, 0, 0);
    }
}

// ---------------------------------------------------------------------------
// Kernel B: attention, cross-tile pipelined. 32 q-rows/wave, 128/block,
// grid 512. Per body(i): prefetch(i+1) | frags(i) | QK^T+softmax(i) |
// PV(i-1) (regs only) | stage(i+1) | barrier.  A/B register sets, 2x unroll.
// ---------------------------------------------------------------------------
__global__ __launch_bounds__(256) void attn_kernel(
    const short* __restrict__ q_ws, const short* __restrict__ k_ws,
    const short* __restrict__ vt_ws, short* __restrict__ o_ws) {
  __shared__ __align__(16) short Ks[2][64 * 64];
  __shared__ __align__(16) short Vs[2][64 * 64];
  const int tid = threadIdx.x, lane = tid & 63, w = tid >> 6;
  const int g = lane >> 4, lr = lane & 15;
  const int bh = blockIdx.y;
  const int q0 = blockIdx.x * 128;
  const short* Qp = q_ws + (long)bh * T * 64;
  const short* Kp = k_ws + (long)bh * T * 64;
  const short* Vt = vt_ws + (long)bh * 64 * T;

  const float c2 = 0.0441941738241592f * 1.4426950408889634f;

  short8 aq[2][2];
#pragma unroll
  for (int mt = 0; mt < 2; ++mt) {
    int r = q0 + w * 32 + mt * 16 + lr;
    aq[mt][0] = *(const short8*)(Qp + (long)r * 64 + g * 8);
    aq[mt][1] = *(const short8*)(Qp + (long)r * 64 + 32 + g * 8);
  }

  floatx4 acc[2][4];
#pragma unroll
  for (int mt = 0; mt < 2; ++mt)
#pragma unroll
    for (int dt = 0; dt < 4; ++dt) acc[mt][dt] = 0;
  float ellp[2] = {0.f, 0.f};

  const int srow = tid >> 2;
  const int sseg = (tid & 3) * 16;

  short8 paA[2][2], paB[2][2], vbA[4][2], vbB[4][2];

  // stage tile 0 -> buf0
  {
    const short8* ksrc = (const short8*)(Kp + (long)srow * 64 + sseg);
    short8 k0 = ksrc[0], k1 = ksrc[1];
    const short8* vsrc = (const short8*)(Vt + (long)srow * T + sseg);
    short8 v0 = vsrc[0], v1 = vsrc[1];
    *(short8*)((char*)Ks[0] + swz(srow, sseg * 2)) = k0;
    *(short8*)((char*)Ks[0] + swz(srow, sseg * 2 + 16)) = k1;
    *(short8*)((char*)Vs[0] + swz(srow, sseg * 2)) = v0;
    *(short8*)((char*)Vs[0] + swz(srow, sseg * 2 + 16)) = v1;
  }
  __syncthreads();

  // BODY(i): process tile i (QK^T+softmax -> paO/vbO), PV for tile i-1 from
  // paP/vbP, stage tile i+1 into buf[(i+1)&1]. DO_PV=0 for the first tile.
#define BODY(IT, paP, vbP, paO, vbO, DO_PV)                                     \
  {                                                                             \
    const int nk = (((IT) + 1) & (NT - 1)) * 64;                                \
    const short8* ksrc = (const short8*)(Kp + (long)(nk + srow) * 64 + sseg);   \
    short8 nk0 = ksrc[0], nk1 = ksrc[1];                                        \
    const short8* vsrc = (const short8*)(Vt + (long)srow * T + nk + sseg);      \
    short8 nv0 = vsrc[0], nv1 = vsrc[1];                                        \
    const char* KsB = (const char*)Ks[(IT) & 1];                                \
    const char* VsB = (const char*)Vs[(IT) & 1];                                \
    short8 kb[4][2];                                                            \
    frag_loads(KsB, VsB, lr, g, kb, vbO);                                       \
    qkt_softmax(kb, aq, c2, ellp, paO);                                         \
    if (DO_PV) do_pv(paP, vbP, acc);                                            \
    char* KsN = (char*)Ks[((IT) + 1) & 1];                                      \
    char* VsN = (char*)Vs[((IT) + 1) & 1];                                      \
    *(short8*)(KsN + swz(srow, sseg * 2)) = nk0;                                \
    *(short8*)(KsN + swz(srow, sseg * 2 + 16)) = nk1;                           \
    *(short8*)(VsN + swz(srow, sseg * 2)) = nv0;                                \
    *(short8*)(VsN + swz(srow, sseg * 2 + 16)) = nv1;                           \
    __syncthreads();                                                            \
  }

  BODY(0, paB, vbB, paA, vbA, 0)            // tile 0 -> A (no PV yet)
  for (int k = 0; k < NT / 2 - 1; ++k) {    // tiles 1..62
    BODY(2 * k + 1, paA, vbA, paB, vbB, 1)
    BODY(2 * k + 2, paB, vbB, paA, vbA, 1)
  }
  BODY(NT - 1, paA, vbA, paB, vbB, 1)       // tile 63
  do_pv(paB, vbB, acc);                     // drain last tile
#undef BODY

  // epilogue: reduce ellp across g-groups, normalize, store
  float ef[2];
#pragma unroll
  for (int mt = 0; mt < 2; ++mt) {
    float e = ellp[mt];
    e += __shfl_xor(e, 16);
    e += __shfl_xor(e, 32);
    ef[mt] = e;
  }
  const int bb = bh >> 3, h = bh & 7;
#pragma unroll
  for (int mt = 0; mt < 2; ++mt) {
#pragma unroll
    for (int j = 0; j < 4; ++j) {
      float rl = 1.0f / __shfl(ef[mt], 4 * g + j);
      int trow = q0 + w * 32 + mt * 16 + 4 * g + j;
      long ob = ((long)(bb * T + trow)) * EMB + h * 64;
#pragma unroll
      for (int dt = 0; dt < 4; ++dt)
        o_ws[ob + dt * 16 + lr] = f2bf(acc[mt][dt][j] * rl);
    }
  }
}

// ---------------------------------------------------------------------------
// Kernel C (verbatim): out[8192][512] = O @ Wu^T + bu (f32 out)
// ---------------------------------------------------------------------------
__global__ __launch_bounds__(256) void proj_kernel(
    const short* __restrict__ o_ws, const float* __restrict__ Wu,
    const float* __restrict__ bu, float* __restrict__ out) {
  __shared__ __align__(16) short As[64 * 64];
  __shared__ __align__(16) short Bs[64 * 64];
  const int tid = threadIdx.x;
  const int lane = tid & 63, w = tid >> 6;
  const int g = lane >> 4, lr = lane & 15;
  const int m0 = blockIdx.x * 64;
  const int n0 = blockIdx.y * 64;

  floatx4 acc[4];
  for (int nt = 0; nt < 4; ++nt) acc[nt] = 0;

  for (int kc = 0; kc < EMB; kc += 64) {
    {
      int row = tid >> 2, kp = (tid & 3) * 16;
      const short8* src = (const short8*)(o_ws + (long)(m0 + row) * EMB + kc + kp);
      short8 v0 = src[0], v1 = src[1];
      *(short8*)((char*)As + swz(row, kp * 2)) = v0;
      *(short8*)((char*)As + swz(row, kp * 2 + 16)) = v1;
    }
    {
      int n = tid >> 2, kp = (tid & 3) * 16;
      const float4* src = (const float4*)(Wu + (long)(n0 + n) * EMB + kc + kp);
      *(short8*)((char*)Bs + swz(n, kp * 2)) = pack8(src[0], src[1]);
      *(short8*)((char*)Bs + swz(n, kp * 2 + 16)) = pack8(src[2], src[3]);
    }
    __syncthreads();

    int arow = w * 16 + lr;
    short8 a0 = *(short8*)((char*)As + swz(arow, g * 16));
    short8 a1 = *(short8*)((char*)As + swz(arow, 64 + g * 16));
    for (int nt = 0; nt < 4; ++nt) {
      int n = nt * 16 + lr;
      short8 b0 = *(short8*)((char*)Bs + swz(n, g * 16));
      short8 b1 = *(short8*)((char*)Bs + swz(n, 64 + g * 16));
      acc[nt] = __builtin_amdgcn_mfma_f32_16x16x32_bf16(a0, b0, acc[nt], 0, 0, 0);
      acc[nt] = __builtin_amdgcn_mfma_f32_16x16x32_bf16(a1, b1, acc[nt], 0, 0, 0);
    }
    __syncthreads();
  }

  for (int nt = 0; nt < 4; ++nt) {
    float bias = bu[n0 + nt * 16 + lr];
    for (int j = 0; j < 4; ++j) {
      int mrow = m0 + w * 16 + 4 * g + j;
      out[(long)mrow * EMB + n0 + nt * 16 + lr] = acc[nt][j] + bias;
    }
  }
}

extern "C" void kernel_launch(void* const* d_in, const int* in_sizes, int n_in,
                              void* d_out, int out_size, void* d_ws, size_t ws_size,
                              hipStream_t stream) {
  const float* x  = (const float*)d_in[0];
  const float* Wq = (const float*)d_in[1];
  const float* Wk = (const float*)d_in[2];
  const float* Wv = (const float*)d_in[3];
  const float* Wu = (const float*)d_in[4];
  const float* bu = (const float*)d_in[5];
  float* out = (float*)d_out;

  const long per = (long)BH * T * 64;
  short* q_ws  = (short*)d_ws;
  short* k_ws  = q_ws + per;
  short* vt_ws = k_ws + per;   // [bh][d][t''] (key-permuted within 32-blocks)
  short* o_ws  = vt_ws + per;  // [8192][512] bf16

  qkv_kernel<<<256, 256, 0, stream>>>(x, Wq, Wk, Wv, q_ws, k_ws, vt_ws);
  attn_kernel<<<dim3(T / 128, BH), 256, 0, stream>>>(q_ws, k_ws, vt_ws, o_ws);
  proj_kernel<<<dim3(BATCH * T / 64, EMB / 64), 256, 0, stream>>>(o_ws, Wu, bu, out);
}